// Round 1
// baseline (441.090 us; speedup 1.0000x reference)
//
#include <hip/hip_runtime.h>

#define TT   2048
#define DD   1024
#define LDK  40           // 32 + 8 pad (keeps 16B alignment for ds_read_b128)

typedef float  f32x4  __attribute__((ext_vector_type(4)));
typedef __bf16 bf16x8 __attribute__((ext_vector_type(8)));

static __device__ __forceinline__ unsigned short f2bf(float f){
  unsigned int u = __float_as_uint(f);
  return (unsigned short)((u + 0x7fffu + ((u >> 16) & 1u)) >> 16);   // RNE
}
static __device__ __forceinline__ float bf2f(unsigned short h){
  return __uint_as_float(((unsigned int)h) << 16);
}
static __device__ __forceinline__ bf16x8 ld8(const unsigned short* p){
  return *(const bf16x8*)p;
}
static __device__ __forceinline__ f32x4 mfma16(bf16x8 a, bf16x8 b, f32x4 c){
  return __builtin_amdgcn_mfma_f32_16x16x32_bf16(a, b, c, 0, 0, 0);
}

// copy 128 rows x 32 cols of bf16(ushort) from global (row-major) into LDS tile [128][LDK]
static __device__ __forceinline__ void stage_u16(
    const unsigned short* __restrict__ src, int row_stride,
    unsigned short* __restrict__ dst, int t)
{
#pragma unroll
  for (int i = 0; i < 2; i++){
    int u = t + i * 256;
    int row = u >> 2, kq = u & 3;
    *(int4*)&dst[row * LDK + kq * 8] =
        *(const int4*)(src + (size_t)row * row_stride + kq * 8);
  }
}

// ---------------- kernel 1: transpose + split W ----------------
__global__ __launch_bounds__(256) void wt_kernel(
    const float* __restrict__ Wq, const float* __restrict__ Wk,
    const float* __restrict__ Wv,
    unsigned short* __restrict__ Wthi, unsigned short* __restrict__ Wtlo)
{
  __shared__ float tile[32][33];
  int z = blockIdx.z;
  const float* W = (z == 0) ? Wq : (z == 1) ? Wk : Wv;
  int k0 = blockIdx.x * 32, n0 = blockIdx.y * 32;
  int tx = threadIdx.x & 31, ty = threadIdx.x >> 5;
#pragma unroll
  for (int r = 0; r < 4; r++){
    int row = ty + r * 8;
    tile[row][tx] = W[(size_t)(k0 + row) * DD + n0 + tx];
  }
  __syncthreads();
  unsigned short* hi = Wthi + (size_t)z * DD * DD;
  unsigned short* lo = Wtlo + (size_t)z * DD * DD;
#pragma unroll
  for (int r = 0; r < 4; r++){
    int nrow = ty + r * 8;
    float v = tile[tx][nrow];                     // = W[k0+tx][n0+nrow]
    unsigned short h = f2bf(v);
    unsigned short l = f2bf(v - bf2f(h));
    size_t idx = (size_t)(n0 + nrow) * DD + k0 + tx;
    hi[idx] = h; lo[idx] = l;
  }
}

// ---------------- kernel 2: projections (split-precision GEMM) ----------------
// z=0: Qhi/Qlo   z=1: Khi/Klo   z=2: V (stored transposed per batch: VT[b][d][t])
__global__ __launch_bounds__(256) void proj_kernel(
    const float* __restrict__ X,
    const unsigned short* __restrict__ Wthi, const unsigned short* __restrict__ Wtlo,
    unsigned short* __restrict__ Qhi, unsigned short* __restrict__ Qlo,
    unsigned short* __restrict__ Khi, unsigned short* __restrict__ Klo,
    unsigned short* __restrict__ VT)
{
  __shared__ unsigned short Ahi[128 * LDK], Alo[128 * LDK];
  __shared__ unsigned short Bhi[128 * LDK], Blo[128 * LDK];
  int z  = blockIdx.z;
  int m0 = blockIdx.y * 128, n0 = blockIdx.x * 128;
  const unsigned short* Bh_g = Wthi + (size_t)z * DD * DD + (size_t)n0 * DD;
  const unsigned short* Bl_g = Wtlo + (size_t)z * DD * DD + (size_t)n0 * DD;
  int t = threadIdx.x;
  int lane = t & 63, w = t >> 6;
  int mw = (w >> 1) << 6, nw = (w & 1) << 6;
  int frow = lane & 15, fk = (lane >> 4) << 3;

  f32x4 acc[4][4];
#pragma unroll
  for (int a = 0; a < 4; a++)
#pragma unroll
    for (int b = 0; b < 4; b++){ f32x4 zz = {0.f,0.f,0.f,0.f}; acc[a][b] = zz; }

  for (int kk = 0; kk < DD / 32; kk++){
    int k0 = kk * 32;
    // stage A (fp32 X -> split bf16)
#pragma unroll
    for (int i = 0; i < 4; i++){
      int f = t + i * 256;
      int row = f >> 3, kq = f & 7;
      const float4 x = *(const float4*)(X + (size_t)(m0 + row) * DD + k0 + kq * 4);
      ushort4 h, l;
      h.x = f2bf(x.x); l.x = f2bf(x.x - bf2f(h.x));
      h.y = f2bf(x.y); l.y = f2bf(x.y - bf2f(h.y));
      h.z = f2bf(x.z); l.z = f2bf(x.z - bf2f(h.z));
      h.w = f2bf(x.w); l.w = f2bf(x.w - bf2f(h.w));
      *(ushort4*)&Ahi[row * LDK + kq * 4] = h;
      *(ushort4*)&Alo[row * LDK + kq * 4] = l;
    }
    // stage B (already-split Wt)
    stage_u16(Bh_g + k0, DD, Bhi, t);
    stage_u16(Bl_g + k0, DD, Blo, t);
    __syncthreads();

    bf16x8 ah[4], al[4], bh[4], bl[4];
#pragma unroll
    for (int tm = 0; tm < 4; tm++){
      int off = (mw + tm * 16 + frow) * LDK + fk;
      ah[tm] = ld8(&Ahi[off]); al[tm] = ld8(&Alo[off]);
    }
#pragma unroll
    for (int tn = 0; tn < 4; tn++){
      int off = (nw + tn * 16 + frow) * LDK + fk;
      bh[tn] = ld8(&Bhi[off]); bl[tn] = ld8(&Blo[off]);
    }
#pragma unroll
    for (int tm = 0; tm < 4; tm++)
#pragma unroll
      for (int tn = 0; tn < 4; tn++){
        acc[tm][tn] = mfma16(ah[tm], bh[tn], acc[tm][tn]);
        if (z < 2){
          acc[tm][tn] = mfma16(ah[tm], bl[tn], acc[tm][tn]);
          acc[tm][tn] = mfma16(al[tm], bh[tn], acc[tm][tn]);
        }
      }
    __syncthreads();
  }

  // epilogue
#pragma unroll
  for (int tm = 0; tm < 4; tm++)
#pragma unroll
    for (int tn = 0; tn < 4; tn++)
#pragma unroll
      for (int r = 0; r < 4; r++){
        float v = acc[tm][tn][r];
        int grow = m0 + mw + tm * 16 + ((lane >> 4) << 2) + r;
        int gcol = n0 + nw + tn * 16 + frow;
        if (z == 0){
          unsigned short h = f2bf(v);
          Qhi[(size_t)grow * DD + gcol] = h;
          Qlo[(size_t)grow * DD + gcol] = f2bf(v - bf2f(h));
        } else if (z == 1){
          unsigned short h = f2bf(v);
          Khi[(size_t)grow * DD + gcol] = h;
          Klo[(size_t)grow * DD + gcol] = f2bf(v - bf2f(h));
        } else {
          int b = grow >> 11, tl = grow & 2047;
          VT[((size_t)(b * DD + gcol) << 11) | tl] = f2bf(v);
        }
      }
}

// ---------------- kernel 3: S = (Q K^T) / 32, causal lower blocks only ----------------
__global__ __launch_bounds__(256) void qk_kernel(
    const unsigned short* __restrict__ Qhi, const unsigned short* __restrict__ Qlo,
    const unsigned short* __restrict__ Khi, const unsigned short* __restrict__ Klo,
    float* __restrict__ S)
{
  if (blockIdx.x > blockIdx.y) return;   // causal: block col > block row -> never read
  __shared__ unsigned short Ahi[128 * LDK], Alo[128 * LDK];
  __shared__ unsigned short Bhi[128 * LDK], Blo[128 * LDK];
  int b  = blockIdx.z;
  int i0 = blockIdx.y * 128, j0 = blockIdx.x * 128;
  const unsigned short* Ah_g = Qhi + (size_t)(b * TT + i0) * DD;
  const unsigned short* Al_g = Qlo + (size_t)(b * TT + i0) * DD;
  const unsigned short* Bh_g = Khi + (size_t)(b * TT + j0) * DD;
  const unsigned short* Bl_g = Klo + (size_t)(b * TT + j0) * DD;
  int t = threadIdx.x;
  int lane = t & 63, w = t >> 6;
  int mw = (w >> 1) << 6, nw = (w & 1) << 6;
  int frow = lane & 15, fk = (lane >> 4) << 3;

  f32x4 acc[4][4];
#pragma unroll
  for (int a = 0; a < 4; a++)
#pragma unroll
    for (int c = 0; c < 4; c++){ f32x4 zz = {0.f,0.f,0.f,0.f}; acc[a][c] = zz; }

  for (int kk = 0; kk < DD / 32; kk++){
    int k0 = kk * 32;
    stage_u16(Ah_g + k0, DD, Ahi, t);
    stage_u16(Al_g + k0, DD, Alo, t);
    stage_u16(Bh_g + k0, DD, Bhi, t);
    stage_u16(Bl_g + k0, DD, Blo, t);
    __syncthreads();

    bf16x8 ah[4], al[4], bh[4], bl[4];
#pragma unroll
    for (int tm = 0; tm < 4; tm++){
      int off = (mw + tm * 16 + frow) * LDK + fk;
      ah[tm] = ld8(&Ahi[off]); al[tm] = ld8(&Alo[off]);
    }
#pragma unroll
    for (int tn = 0; tn < 4; tn++){
      int off = (nw + tn * 16 + frow) * LDK + fk;
      bh[tn] = ld8(&Bhi[off]); bl[tn] = ld8(&Blo[off]);
    }
#pragma unroll
    for (int tm = 0; tm < 4; tm++)
#pragma unroll
      for (int tn = 0; tn < 4; tn++){
        acc[tm][tn] = mfma16(ah[tm], bh[tn], acc[tm][tn]);
        acc[tm][tn] = mfma16(ah[tm], bl[tn], acc[tm][tn]);
        acc[tm][tn] = mfma16(al[tm], bh[tn], acc[tm][tn]);
      }
    __syncthreads();
  }

#pragma unroll
  for (int tm = 0; tm < 4; tm++)
#pragma unroll
    for (int tn = 0; tn < 4; tn++)
#pragma unroll
      for (int r = 0; r < 4; r++){
        int gi = i0 + mw + tm * 16 + ((lane >> 4) << 2) + r;
        int gj = j0 + nw + tn * 16 + frow;
        S[((size_t)(b * TT + gi) * TT) + gj] = acc[tm][tn][r] * 0.03125f;
      }
}

// ---------------- kernel 4: row softmax (index-masked), P in bf16 ----------------
__global__ __launch_bounds__(256) void softmax_kernel(
    const float* __restrict__ S, unsigned short* __restrict__ P)
{
  int i = blockIdx.x, b = blockIdx.y;
  const float* s = S + (size_t)(b * TT + i) * TT;
  unsigned short* p = P + (size_t)(b * TT + i) * TT;
  int n = i + 1;
  int npad = ((i >> 7) + 1) << 7;   // pad to end of the diagonal 128-block
  int t = threadIdx.x;
  __shared__ float red[256];

  float mx = -1e30f;
  for (int j = t; j < n; j += 256) mx = fmaxf(mx, s[j]);
  red[t] = mx; __syncthreads();
  for (int k = 128; k > 0; k >>= 1){ if (t < k) red[t] = fmaxf(red[t], red[t + k]); __syncthreads(); }
  mx = red[0]; __syncthreads();

  float sum = 0.f;
  for (int j = t; j < n; j += 256) sum += __expf(s[j] - mx);
  red[t] = sum; __syncthreads();
  for (int k = 128; k > 0; k >>= 1){ if (t < k) red[t] += red[t + k]; __syncthreads(); }
  float inv = 1.0f / red[0];

  for (int j = t; j < npad; j += 256){
    float v = (j < n) ? __expf(s[j] - mx) * inv : 0.0f;
    p[j] = f2bf(v);
  }
}

// ---------------- kernel 5: O = P V  (plain bf16, causal K-range) ----------------
__global__ __launch_bounds__(256) void pv_kernel(
    const unsigned short* __restrict__ P, const unsigned short* __restrict__ VT,
    float* __restrict__ O)
{
  __shared__ unsigned short At[128 * LDK];
  __shared__ unsigned short Bt[128 * LDK];
  int b  = blockIdx.z;
  int i0 = blockIdx.y * 128, n0 = blockIdx.x * 128;
  int ksteps = (blockIdx.y + 1) * 4;   // K runs over s < (i_blk+1)*128
  const unsigned short* A_g = P  + (size_t)(b * TT + i0) * TT;
  const unsigned short* B_g = VT + (size_t)(b * DD + n0) * TT;
  int t = threadIdx.x;
  int lane = t & 63, w = t >> 6;
  int mw = (w >> 1) << 6, nw = (w & 1) << 6;
  int frow = lane & 15, fk = (lane >> 4) << 3;

  f32x4 acc[4][4];
#pragma unroll
  for (int a = 0; a < 4; a++)
#pragma unroll
    for (int c = 0; c < 4; c++){ f32x4 zz = {0.f,0.f,0.f,0.f}; acc[a][c] = zz; }

  for (int kk = 0; kk < ksteps; kk++){
    int k0 = kk * 32;
    stage_u16(A_g + k0, TT, At, t);
    stage_u16(B_g + k0, TT, Bt, t);
    __syncthreads();

    bf16x8 af[4], bf[4];
#pragma unroll
    for (int tm = 0; tm < 4; tm++) af[tm] = ld8(&At[(mw + tm * 16 + frow) * LDK + fk]);
#pragma unroll
    for (int tn = 0; tn < 4; tn++) bf[tn] = ld8(&Bt[(nw + tn * 16 + frow) * LDK + fk]);
#pragma unroll
    for (int tm = 0; tm < 4; tm++)
#pragma unroll
      for (int tn = 0; tn < 4; tn++)
        acc[tm][tn] = mfma16(af[tm], bf[tn], acc[tm][tn]);
    __syncthreads();
  }

#pragma unroll
  for (int tm = 0; tm < 4; tm++)
#pragma unroll
    for (int tn = 0; tn < 4; tn++)
#pragma unroll
      for (int r = 0; r < 4; r++){
        int gi = i0 + mw + tm * 16 + ((lane >> 4) << 2) + r;
        int gd = n0 + nw + tn * 16 + frow;
        O[(size_t)(b * TT + gi) * DD + gd] = acc[tm][tn][r];
      }
}

extern "C" void kernel_launch(void* const* d_in, const int* in_sizes, int n_in,
                              void* d_out, int out_size, void* d_ws, size_t ws_size,
                              hipStream_t stream) {
  const float* X  = (const float*)d_in[0];
  const float* Wq = (const float*)d_in[1];
  const float* Wk = (const float*)d_in[2];
  const float* Wv = (const float*)d_in[3];
  float* Out = (float*)d_out;

  unsigned short* Wthi = (unsigned short*)d_ws;          // 3 * 1M
  unsigned short* Wtlo = Wthi + 3u * 1048576u;           // 3 * 1M
  unsigned short* Qhi  = Wtlo + 3u * 1048576u;           // 8M each below
  unsigned short* Qlo  = Qhi + 8388608u;
  unsigned short* Khi  = Qlo + 8388608u;
  unsigned short* Klo  = Khi + 8388608u;
  unsigned short* VT   = Klo + 8388608u;
  float*          S    = (float*)(VT + 8388608u);        // 16M floats (64 MB)
  unsigned short* P    = (unsigned short*)(S + 16777216u); // 16M bf16 (32 MB)
  // total ws use ~188 MB

  dim3 blk(256);
  wt_kernel<<<dim3(32, 32, 3), blk, 0, stream>>>(Wq, Wk, Wv, Wthi, Wtlo);
  proj_kernel<<<dim3(8, 64, 3), blk, 0, stream>>>(X, Wthi, Wtlo, Qhi, Qlo, Khi, Klo, VT);
  qk_kernel<<<dim3(16, 16, 4), blk, 0, stream>>>(Qhi, Qlo, Khi, Klo, S);
  softmax_kernel<<<dim3(2048, 4, 1), blk, 0, stream>>>(S, P);
  pv_kernel<<<dim3(8, 16, 4), blk, 0, stream>>>(P, VT, Out);
}

// Round 2
// 401.758 us; speedup vs baseline: 1.0979x; 1.0979x over previous
//
#include <hip/hip_runtime.h>

#define TT   2048
#define DD   1024
#define BK   32          // K-tile; LDS tiles are contiguous [128][32] (global_load_lds needs lane-order layout)

typedef float  f32x4  __attribute__((ext_vector_type(4)));
typedef __bf16 bf16x8 __attribute__((ext_vector_type(8)));

static __device__ __forceinline__ unsigned short f2bf(float f){
  unsigned int u = __float_as_uint(f);
  return (unsigned short)((u + 0x7fffu + ((u >> 16) & 1u)) >> 16);   // RNE
}
static __device__ __forceinline__ float bf2f(unsigned short h){
  return __uint_as_float(((unsigned int)h) << 16);
}
static __device__ __forceinline__ bf16x8 ld8(const unsigned short* p){
  return *(const bf16x8*)p;
}
static __device__ __forceinline__ f32x4 mfma16(bf16x8 a, bf16x8 b, f32x4 c){
  return __builtin_amdgcn_mfma_f32_16x16x32_bf16(a, b, c, 0, 0, 0);
}

// async 16B global->LDS (direct, no VGPR round-trip)
static __device__ __forceinline__ void async16(
    const unsigned short* g, unsigned short* l)
{
  __builtin_amdgcn_global_load_lds(
      (const __attribute__((address_space(1))) unsigned int*)g,
      (__attribute__((address_space(3))) unsigned int*)l, 16, 0, 0);
}

// stage 128 rows x 32 cols of ushort from global (row-major, row_stride) into
// contiguous LDS tile [128][32]. Per thread: 2 x 16B. LDS dst = wave base + lane*16. ✓
static __device__ __forceinline__ void stage_async(
    const unsigned short* __restrict__ src, int row_stride,
    unsigned short* __restrict__ dst, int t)
{
#pragma unroll
  for (int j = 0; j < 2; j++){
    int e = (t + j * 256) * 8;          // ushort index in tile
    int row = e >> 5, col = e & 31;
    async16(src + (size_t)row * row_stride + col, dst + e);
  }
}

// ---------------- kernel 0: split X into hi/lo bf16 ----------------
__global__ __launch_bounds__(256) void splitx_kernel(
    const float* __restrict__ X,
    unsigned short* __restrict__ Xhi, unsigned short* __restrict__ Xlo)
{
  size_t i = ((size_t)blockIdx.x * 256 + threadIdx.x) * 4;
  const float4 x = *(const float4*)(X + i);
  ushort4 h, l;
  h.x = f2bf(x.x); l.x = f2bf(x.x - bf2f(h.x));
  h.y = f2bf(x.y); l.y = f2bf(x.y - bf2f(h.y));
  h.z = f2bf(x.z); l.z = f2bf(x.z - bf2f(h.z));
  h.w = f2bf(x.w); l.w = f2bf(x.w - bf2f(h.w));
  *(ushort4*)(Xhi + i) = h;
  *(ushort4*)(Xlo + i) = l;
}

// ---------------- kernel 1: transpose + split W ----------------
__global__ __launch_bounds__(256) void wt_kernel(
    const float* __restrict__ Wq, const float* __restrict__ Wk,
    const float* __restrict__ Wv,
    unsigned short* __restrict__ Wthi, unsigned short* __restrict__ Wtlo)
{
  __shared__ float tile[32][33];
  int z = blockIdx.z;
  const float* W = (z == 0) ? Wq : (z == 1) ? Wk : Wv;
  int k0 = blockIdx.x * 32, n0 = blockIdx.y * 32;
  int tx = threadIdx.x & 31, ty = threadIdx.x >> 5;
#pragma unroll
  for (int r = 0; r < 4; r++){
    int row = ty + r * 8;
    tile[row][tx] = W[(size_t)(k0 + row) * DD + n0 + tx];
  }
  __syncthreads();
  unsigned short* hi = Wthi + (size_t)z * DD * DD;
  unsigned short* lo = Wtlo + (size_t)z * DD * DD;
#pragma unroll
  for (int r = 0; r < 4; r++){
    int nrow = ty + r * 8;
    float v = tile[tx][nrow];                     // = W[k0+tx][n0+nrow]
    unsigned short h = f2bf(v);
    unsigned short l = f2bf(v - bf2f(h));
    size_t idx = (size_t)(n0 + nrow) * DD + k0 + tx;
    hi[idx] = h; lo[idx] = l;
  }
}

// ---------------- kernel 2: projections (split-precision GEMM) ----------------
// z=0: Qhi/Qlo   z=1: Khi/Klo   z=2: V (stored transposed per batch: VT[b][d][t])
__global__ __launch_bounds__(256) void proj_kernel(
    const unsigned short* __restrict__ Xhi, const unsigned short* __restrict__ Xlo,
    const unsigned short* __restrict__ Wthi, const unsigned short* __restrict__ Wtlo,
    unsigned short* __restrict__ Qhi, unsigned short* __restrict__ Qlo,
    unsigned short* __restrict__ Khi, unsigned short* __restrict__ Klo,
    unsigned short* __restrict__ VT)
{
  __shared__ unsigned short Ahi[128 * BK], Alo[128 * BK];
  __shared__ unsigned short Bhi[128 * BK], Blo[128 * BK];
  int z  = blockIdx.z;
  int m0 = blockIdx.y * 128, n0 = blockIdx.x * 128;
  const unsigned short* Ah_g = Xhi + (size_t)m0 * DD;
  const unsigned short* Al_g = Xlo + (size_t)m0 * DD;
  const unsigned short* Bh_g = Wthi + (size_t)z * DD * DD + (size_t)n0 * DD;
  const unsigned short* Bl_g = Wtlo + (size_t)z * DD * DD + (size_t)n0 * DD;
  int t = threadIdx.x;
  int lane = t & 63, w = t >> 6;
  int mw = (w >> 1) << 6, nw = (w & 1) << 6;
  int frow = lane & 15, fk = (lane >> 4) << 3;

  f32x4 acc[4][4];
#pragma unroll
  for (int a = 0; a < 4; a++)
#pragma unroll
    for (int b = 0; b < 4; b++){ f32x4 zz = {0.f,0.f,0.f,0.f}; acc[a][b] = zz; }

  for (int kk = 0; kk < DD / BK; kk++){
    int k0 = kk * BK;
    stage_async(Ah_g + k0, DD, Ahi, t);
    stage_async(Bh_g + k0, DD, Bhi, t);
    if (z < 2){
      stage_async(Al_g + k0, DD, Alo, t);
      stage_async(Bl_g + k0, DD, Blo, t);
    }
    __syncthreads();

    bf16x8 ah[4], al[4], bh[4], bl[4];
#pragma unroll
    for (int tm = 0; tm < 4; tm++){
      int off = (mw + tm * 16 + frow) * BK + fk;
      ah[tm] = ld8(&Ahi[off]);
      if (z < 2) al[tm] = ld8(&Alo[off]);
    }
#pragma unroll
    for (int tn = 0; tn < 4; tn++){
      int off = (nw + tn * 16 + frow) * BK + fk;
      bh[tn] = ld8(&Bhi[off]);
      if (z < 2) bl[tn] = ld8(&Blo[off]);
    }
#pragma unroll
    for (int tm = 0; tm < 4; tm++)
#pragma unroll
      for (int tn = 0; tn < 4; tn++){
        acc[tm][tn] = mfma16(ah[tm], bh[tn], acc[tm][tn]);
        if (z < 2){
          acc[tm][tn] = mfma16(ah[tm], bl[tn], acc[tm][tn]);
          acc[tm][tn] = mfma16(al[tm], bh[tn], acc[tm][tn]);
        }
      }
    __syncthreads();
  }

  // epilogue
#pragma unroll
  for (int tm = 0; tm < 4; tm++)
#pragma unroll
    for (int tn = 0; tn < 4; tn++)
#pragma unroll
      for (int r = 0; r < 4; r++){
        float v = acc[tm][tn][r];
        int grow = m0 + mw + tm * 16 + ((lane >> 4) << 2) + r;
        int gcol = n0 + nw + tn * 16 + frow;
        if (z == 0){
          unsigned short h = f2bf(v);
          Qhi[(size_t)grow * DD + gcol] = h;
          Qlo[(size_t)grow * DD + gcol] = f2bf(v - bf2f(h));
        } else if (z == 1){
          unsigned short h = f2bf(v);
          Khi[(size_t)grow * DD + gcol] = h;
          Klo[(size_t)grow * DD + gcol] = f2bf(v - bf2f(h));
        } else {
          int b = grow >> 11, tl = grow & 2047;
          VT[((size_t)(b * DD + gcol) << 11) | tl] = f2bf(v);
        }
      }
}

// ---------------- kernel 3: S = (Q K^T) / 32, causal lower blocks only ----------------
__global__ __launch_bounds__(256) void qk_kernel(
    const unsigned short* __restrict__ Qhi, const unsigned short* __restrict__ Qlo,
    const unsigned short* __restrict__ Khi, const unsigned short* __restrict__ Klo,
    float* __restrict__ S)
{
  if (blockIdx.x > blockIdx.y) return;   // causal: block col > block row -> never read
  __shared__ unsigned short Ahi[128 * BK], Alo[128 * BK];
  __shared__ unsigned short Bhi[128 * BK], Blo[128 * BK];
  int b  = blockIdx.z;
  int i0 = blockIdx.y * 128, j0 = blockIdx.x * 128;
  const unsigned short* Ah_g = Qhi + (size_t)(b * TT + i0) * DD;
  const unsigned short* Al_g = Qlo + (size_t)(b * TT + i0) * DD;
  const unsigned short* Bh_g = Khi + (size_t)(b * TT + j0) * DD;
  const unsigned short* Bl_g = Klo + (size_t)(b * TT + j0) * DD;
  int t = threadIdx.x;
  int lane = t & 63, w = t >> 6;
  int mw = (w >> 1) << 6, nw = (w & 1) << 6;
  int frow = lane & 15, fk = (lane >> 4) << 3;

  f32x4 acc[4][4];
#pragma unroll
  for (int a = 0; a < 4; a++)
#pragma unroll
    for (int c = 0; c < 4; c++){ f32x4 zz = {0.f,0.f,0.f,0.f}; acc[a][c] = zz; }

  for (int kk = 0; kk < DD / BK; kk++){
    int k0 = kk * BK;
    stage_async(Ah_g + k0, DD, Ahi, t);
    stage_async(Al_g + k0, DD, Alo, t);
    stage_async(Bh_g + k0, DD, Bhi, t);
    stage_async(Bl_g + k0, DD, Blo, t);
    __syncthreads();

    bf16x8 ah[4], al[4], bh[4], bl[4];
#pragma unroll
    for (int tm = 0; tm < 4; tm++){
      int off = (mw + tm * 16 + frow) * BK + fk;
      ah[tm] = ld8(&Ahi[off]); al[tm] = ld8(&Alo[off]);
    }
#pragma unroll
    for (int tn = 0; tn < 4; tn++){
      int off = (nw + tn * 16 + frow) * BK + fk;
      bh[tn] = ld8(&Bhi[off]); bl[tn] = ld8(&Blo[off]);
    }
#pragma unroll
    for (int tm = 0; tm < 4; tm++)
#pragma unroll
      for (int tn = 0; tn < 4; tn++){
        acc[tm][tn] = mfma16(ah[tm], bh[tn], acc[tm][tn]);
        acc[tm][tn] = mfma16(ah[tm], bl[tn], acc[tm][tn]);
        acc[tm][tn] = mfma16(al[tm], bh[tn], acc[tm][tn]);
      }
    __syncthreads();
  }

#pragma unroll
  for (int tm = 0; tm < 4; tm++)
#pragma unroll
    for (int tn = 0; tn < 4; tn++)
#pragma unroll
      for (int r = 0; r < 4; r++){
        int gi = i0 + mw + tm * 16 + ((lane >> 4) << 2) + r;
        int gj = j0 + nw + tn * 16 + frow;
        S[((size_t)(b * TT + gi) * TT) + gj] = acc[tm][tn][r] * 0.03125f;
      }
}

// ---------------- kernel 4: row softmax, single pass over S, P in bf16 ----------------
__global__ __launch_bounds__(256) void softmax_kernel(
    const float* __restrict__ S, unsigned short* __restrict__ P)
{
  int i = blockIdx.x, b = blockIdx.y;
  const float* s = S + (size_t)(b * TT + i) * TT;
  unsigned short* p = P + (size_t)(b * TT + i) * TT;
  int n = i + 1;
  int npad = ((i >> 7) + 1) << 7;   // pad to end of the diagonal 128-block
  int t = threadIdx.x;
  __shared__ float red[256];

  float v[8];
  float mx = -1e30f;
#pragma unroll
  for (int j = 0; j < 8; j++){
    int idx = t + j * 256;
    v[j] = (idx < n) ? s[idx] : -1e30f;
    mx = fmaxf(mx, v[j]);
  }
  red[t] = mx; __syncthreads();
  for (int k = 128; k > 0; k >>= 1){ if (t < k) red[t] = fmaxf(red[t], red[t + k]); __syncthreads(); }
  mx = red[0]; __syncthreads();

  float sum = 0.f;
#pragma unroll
  for (int j = 0; j < 8; j++){
    v[j] = (t + j * 256 < n) ? __expf(v[j] - mx) : 0.0f;
    sum += v[j];
  }
  red[t] = sum; __syncthreads();
  for (int k = 128; k > 0; k >>= 1){ if (t < k) red[t] += red[t + k]; __syncthreads(); }
  float inv = 1.0f / red[0];

#pragma unroll
  for (int j = 0; j < 8; j++){
    int idx = t + j * 256;
    if (idx < npad) p[idx] = f2bf(v[j] * inv);
  }
}

// ---------------- kernel 5: O = P V  (plain bf16, causal K-range) ----------------
__global__ __launch_bounds__(256) void pv_kernel(
    const unsigned short* __restrict__ P, const unsigned short* __restrict__ VT,
    float* __restrict__ O)
{
  __shared__ unsigned short At[128 * BK];
  __shared__ unsigned short Bt[128 * BK];
  int b  = blockIdx.z;
  int i0 = blockIdx.y * 128, n0 = blockIdx.x * 128;
  int ksteps = (blockIdx.y + 1) * 4;   // K runs over s < (i_blk+1)*128
  const unsigned short* A_g = P  + (size_t)(b * TT + i0) * TT;
  const unsigned short* B_g = VT + (size_t)(b * DD + n0) * TT;
  int t = threadIdx.x;
  int lane = t & 63, w = t >> 6;
  int mw = (w >> 1) << 6, nw = (w & 1) << 6;
  int frow = lane & 15, fk = (lane >> 4) << 3;

  f32x4 acc[4][4];
#pragma unroll
  for (int a = 0; a < 4; a++)
#pragma unroll
    for (int c = 0; c < 4; c++){ f32x4 zz = {0.f,0.f,0.f,0.f}; acc[a][c] = zz; }

  for (int kk = 0; kk < ksteps; kk++){
    int k0 = kk * BK;
    stage_async(A_g + k0, TT, At, t);
    stage_async(B_g + k0, TT, Bt, t);
    __syncthreads();

    bf16x8 af[4], bf[4];
#pragma unroll
    for (int tm = 0; tm < 4; tm++) af[tm] = ld8(&At[(mw + tm * 16 + frow) * BK + fk]);
#pragma unroll
    for (int tn = 0; tn < 4; tn++) bf[tn] = ld8(&Bt[(nw + tn * 16 + frow) * BK + fk]);
#pragma unroll
    for (int tm = 0; tm < 4; tm++)
#pragma unroll
      for (int tn = 0; tn < 4; tn++)
        acc[tm][tn] = mfma16(af[tm], bf[tn], acc[tm][tn]);
    __syncthreads();
  }

#pragma unroll
  for (int tm = 0; tm < 4; tm++)
#pragma unroll
    for (int tn = 0; tn < 4; tn++)
#pragma unroll
      for (int r = 0; r < 4; r++){
        int gi = i0 + mw + tm * 16 + ((lane >> 4) << 2) + r;
        int gd = n0 + nw + tn * 16 + frow;
        O[(size_t)(b * TT + gi) * DD + gd] = acc[tm][tn][r];
      }
}

extern "C" void kernel_launch(void* const* d_in, const int* in_sizes, int n_in,
                              void* d_out, int out_size, void* d_ws, size_t ws_size,
                              hipStream_t stream) {
  const float* X  = (const float*)d_in[0];
  const float* Wq = (const float*)d_in[1];
  const float* Wk = (const float*)d_in[2];
  const float* Wv = (const float*)d_in[3];
  float* Out = (float*)d_out;

  unsigned short* Wthi = (unsigned short*)d_ws;          // 3 * 1M ushorts
  unsigned short* Wtlo = Wthi + 3u * 1048576u;           // 3 * 1M
  unsigned short* Qhi  = Wtlo + 3u * 1048576u;           // 8M ushorts each below
  unsigned short* Qlo  = Qhi + 8388608u;
  unsigned short* Khi  = Qlo + 8388608u;
  unsigned short* Klo  = Khi + 8388608u;
  unsigned short* VT   = Klo + 8388608u;
  float*          S    = (float*)(VT + 8388608u);        // 16M floats (64 MB)
  unsigned short* P    = (unsigned short*)(S + 16777216u); // 16M bf16 (32 MB)
  // Xhi/Xlo alias the S region (S is first written by qk_kernel, after proj_kernel
  // has finished reading Xhi/Xlo) -> total ws stays ~188 MB.
  unsigned short* Xhi  = (unsigned short*)S;             // 8M ushorts
  unsigned short* Xlo  = Xhi + 8388608u;                 // 8M ushorts

  dim3 blk(256);
  splitx_kernel<<<dim3(8192), blk, 0, stream>>>(X, Xhi, Xlo);
  wt_kernel<<<dim3(32, 32, 3), blk, 0, stream>>>(Wq, Wk, Wv, Wthi, Wtlo);
  proj_kernel<<<dim3(8, 64, 3), blk, 0, stream>>>(Xhi, Xlo, Wthi, Wtlo, Qhi, Qlo, Khi, Klo, VT);
  qk_kernel<<<dim3(16, 16, 4), blk, 0, stream>>>(Qhi, Qlo, Khi, Klo, S);
  softmax_kernel<<<dim3(2048, 4, 1), blk, 0, stream>>>(S, P);
  pv_kernel<<<dim3(8, 16, 4), blk, 0, stream>>>(P, VT, Out);
}

// Round 3
// 385.272 us; speedup vs baseline: 1.1449x; 1.0428x over previous
//
#include <hip/hip_runtime.h>

#define TT   2048
#define DD   1024
#define BK   32          // K-tile; LDS tiles are contiguous [128][32] (global_load_lds needs lane-order layout)

typedef float  f32x4  __attribute__((ext_vector_type(4)));
typedef __bf16 bf16x8 __attribute__((ext_vector_type(8)));

static __device__ __forceinline__ unsigned short f2bf(float f){
  unsigned int u = __float_as_uint(f);
  return (unsigned short)((u + 0x7fffu + ((u >> 16) & 1u)) >> 16);   // RNE
}
static __device__ __forceinline__ float bf2f(unsigned short h){
  return __uint_as_float(((unsigned int)h) << 16);
}
static __device__ __forceinline__ bf16x8 ld8(const unsigned short* p){
  return *(const bf16x8*)p;
}
static __device__ __forceinline__ f32x4 mfma16(bf16x8 a, bf16x8 b, f32x4 c){
  return __builtin_amdgcn_mfma_f32_16x16x32_bf16(a, b, c, 0, 0, 0);
}

// async 16B global->LDS (direct, no VGPR round-trip)
static __device__ __forceinline__ void async16(
    const unsigned short* g, unsigned short* l)
{
  __builtin_amdgcn_global_load_lds(
      (const __attribute__((address_space(1))) unsigned int*)g,
      (__attribute__((address_space(3))) unsigned int*)l, 16, 0, 0);
}

// stage 128 rows x 32 cols of ushort from global (row-major, row_stride) into
// contiguous LDS tile [128][32]. Per thread: 2 x 16B. LDS dst = wave base + lane*16. ✓
static __device__ __forceinline__ void stage_async(
    const unsigned short* __restrict__ src, int row_stride,
    unsigned short* __restrict__ dst, int t)
{
#pragma unroll
  for (int j = 0; j < 2; j++){
    int e = (t + j * 256) * 8;          // ushort index in tile
    int row = e >> 5, col = e & 31;
    async16(src + (size_t)row * row_stride + col, dst + e);
  }
}

// ---------------- kernel 0: split X into hi/lo bf16 ----------------
__global__ __launch_bounds__(256) void splitx_kernel(
    const float* __restrict__ X,
    unsigned short* __restrict__ Xhi, unsigned short* __restrict__ Xlo)
{
  size_t i = ((size_t)blockIdx.x * 256 + threadIdx.x) * 4;
  const float4 x = *(const float4*)(X + i);
  ushort4 h, l;
  h.x = f2bf(x.x); l.x = f2bf(x.x - bf2f(h.x));
  h.y = f2bf(x.y); l.y = f2bf(x.y - bf2f(h.y));
  h.z = f2bf(x.z); l.z = f2bf(x.z - bf2f(h.z));
  h.w = f2bf(x.w); l.w = f2bf(x.w - bf2f(h.w));
  *(ushort4*)(Xhi + i) = h;
  *(ushort4*)(Xlo + i) = l;
}

// ---------------- kernel 1: transpose + split W ----------------
__global__ __launch_bounds__(256) void wt_kernel(
    const float* __restrict__ Wq, const float* __restrict__ Wk,
    const float* __restrict__ Wv,
    unsigned short* __restrict__ Wthi, unsigned short* __restrict__ Wtlo)
{
  __shared__ float tile[32][33];
  int z = blockIdx.z;
  const float* W = (z == 0) ? Wq : (z == 1) ? Wk : Wv;
  int k0 = blockIdx.x * 32, n0 = blockIdx.y * 32;
  int tx = threadIdx.x & 31, ty = threadIdx.x >> 5;
#pragma unroll
  for (int r = 0; r < 4; r++){
    int row = ty + r * 8;
    tile[row][tx] = W[(size_t)(k0 + row) * DD + n0 + tx];
  }
  __syncthreads();
  unsigned short* hi = Wthi + (size_t)z * DD * DD;
  unsigned short* lo = Wtlo + (size_t)z * DD * DD;
#pragma unroll
  for (int r = 0; r < 4; r++){
    int nrow = ty + r * 8;
    float v = tile[tx][nrow];                     // = W[k0+tx][n0+nrow]
    unsigned short h = f2bf(v);
    unsigned short l = f2bf(v - bf2f(h));
    size_t idx = (size_t)(n0 + nrow) * DD + k0 + tx;
    hi[idx] = h; lo[idx] = l;
  }
}

// ---------------- kernel 2: projections ----------------
// z=0: Q and K merged (split-precision, shared A staging, 96 MFMA/barrier)
// z=1: V (plain bf16, stored transposed per batch: VT[b][d][t])
__global__ __launch_bounds__(256, 2) void proj_kernel(
    const unsigned short* __restrict__ Xhi, const unsigned short* __restrict__ Xlo,
    const unsigned short* __restrict__ Wthi, const unsigned short* __restrict__ Wtlo,
    unsigned short* __restrict__ Qhi, unsigned short* __restrict__ Qlo,
    unsigned short* __restrict__ Khi, unsigned short* __restrict__ Klo,
    unsigned short* __restrict__ VT)
{
  __shared__ unsigned short Ahi[128 * BK], Alo[128 * BK];
  __shared__ unsigned short Bqh[128 * BK], Bql[128 * BK];
  __shared__ unsigned short Bkh[128 * BK], Bkl[128 * BK];
  int m0 = blockIdx.y * 128, n0 = blockIdx.x * 128;
  int t = threadIdx.x;
  int lane = t & 63, w = t >> 6;
  int mw = (w >> 1) << 6, nw = (w & 1) << 6;
  int frow = lane & 15, fk = (lane >> 4) << 3;
  const unsigned short* Ah_g = Xhi + (size_t)m0 * DD;
  const unsigned short* Al_g = Xlo + (size_t)m0 * DD;

  if (blockIdx.z == 0){
    // ---- merged Q & K ----
    const unsigned short* Bqh_g = Wthi + (size_t)n0 * DD;
    const unsigned short* Bql_g = Wtlo + (size_t)n0 * DD;
    const unsigned short* Bkh_g = Wthi + (size_t)DD * DD + (size_t)n0 * DD;
    const unsigned short* Bkl_g = Wtlo + (size_t)DD * DD + (size_t)n0 * DD;

    f32x4 accQ[4][4], accK[4][4];
#pragma unroll
    for (int a = 0; a < 4; a++)
#pragma unroll
      for (int b = 0; b < 4; b++){
        f32x4 zz = {0.f,0.f,0.f,0.f}; accQ[a][b] = zz; accK[a][b] = zz;
      }

    for (int kk = 0; kk < DD / BK; kk++){
      int k0 = kk * BK;
      stage_async(Ah_g + k0, DD, Ahi, t);
      stage_async(Al_g + k0, DD, Alo, t);
      stage_async(Bqh_g + k0, DD, Bqh, t);
      stage_async(Bql_g + k0, DD, Bql, t);
      stage_async(Bkh_g + k0, DD, Bkh, t);
      stage_async(Bkl_g + k0, DD, Bkl, t);
      __syncthreads();

      bf16x8 ah[4], al[4];
#pragma unroll
      for (int tm = 0; tm < 4; tm++){
        int off = (mw + tm * 16 + frow) * BK + fk;
        ah[tm] = ld8(&Ahi[off]); al[tm] = ld8(&Alo[off]);
      }
#pragma unroll
      for (int tn = 0; tn < 4; tn++){
        int off = (nw + tn * 16 + frow) * BK + fk;
        bf16x8 bqh = ld8(&Bqh[off]), bql = ld8(&Bql[off]);
        bf16x8 bkh = ld8(&Bkh[off]), bkl = ld8(&Bkl[off]);
#pragma unroll
        for (int tm = 0; tm < 4; tm++){
          accQ[tm][tn] = mfma16(ah[tm], bqh, accQ[tm][tn]);
          accQ[tm][tn] = mfma16(ah[tm], bql, accQ[tm][tn]);
          accQ[tm][tn] = mfma16(al[tm], bqh, accQ[tm][tn]);
          accK[tm][tn] = mfma16(ah[tm], bkh, accK[tm][tn]);
          accK[tm][tn] = mfma16(ah[tm], bkl, accK[tm][tn]);
          accK[tm][tn] = mfma16(al[tm], bkh, accK[tm][tn]);
        }
      }
      __syncthreads();
    }

#pragma unroll
    for (int tm = 0; tm < 4; tm++)
#pragma unroll
      for (int tn = 0; tn < 4; tn++)
#pragma unroll
        for (int r = 0; r < 4; r++){
          int grow = m0 + mw + tm * 16 + ((lane >> 4) << 2) + r;
          int gcol = n0 + nw + tn * 16 + frow;
          size_t idx = (size_t)grow * DD + gcol;
          float vq = accQ[tm][tn][r];
          unsigned short hq = f2bf(vq);
          Qhi[idx] = hq; Qlo[idx] = f2bf(vq - bf2f(hq));
          float vk = accK[tm][tn][r];
          unsigned short hk = f2bf(vk);
          Khi[idx] = hk; Klo[idx] = f2bf(vk - bf2f(hk));
        }
  } else {
    // ---- V (plain bf16) ----
    const unsigned short* Bvh_g = Wthi + 2 * (size_t)DD * DD + (size_t)n0 * DD;
    f32x4 acc[4][4];
#pragma unroll
    for (int a = 0; a < 4; a++)
#pragma unroll
      for (int b = 0; b < 4; b++){ f32x4 zz = {0.f,0.f,0.f,0.f}; acc[a][b] = zz; }

    for (int kk = 0; kk < DD / BK; kk++){
      int k0 = kk * BK;
      stage_async(Ah_g + k0, DD, Ahi, t);
      stage_async(Bvh_g + k0, DD, Bqh, t);
      __syncthreads();

      bf16x8 ah[4], bh[4];
#pragma unroll
      for (int tm = 0; tm < 4; tm++) ah[tm] = ld8(&Ahi[(mw + tm * 16 + frow) * BK + fk]);
#pragma unroll
      for (int tn = 0; tn < 4; tn++) bh[tn] = ld8(&Bqh[(nw + tn * 16 + frow) * BK + fk]);
#pragma unroll
      for (int tm = 0; tm < 4; tm++)
#pragma unroll
        for (int tn = 0; tn < 4; tn++)
          acc[tm][tn] = mfma16(ah[tm], bh[tn], acc[tm][tn]);
      __syncthreads();
    }

#pragma unroll
    for (int tm = 0; tm < 4; tm++)
#pragma unroll
      for (int tn = 0; tn < 4; tn++)
#pragma unroll
        for (int r = 0; r < 4; r++){
          int grow = m0 + mw + tm * 16 + ((lane >> 4) << 2) + r;
          int gcol = n0 + nw + tn * 16 + frow;
          int b = grow >> 11, tl = grow & 2047;
          VT[((size_t)(b * DD + gcol) << 11) | tl] = f2bf(acc[tm][tn][r]);
        }
  }
}

// ---------------- kernel 3: S = (Q K^T) / 32, triangular grid (no dead blocks) ----------------
__global__ __launch_bounds__(256) void qk_kernel(
    const unsigned short* __restrict__ Qhi, const unsigned short* __restrict__ Qlo,
    const unsigned short* __restrict__ Khi, const unsigned short* __restrict__ Klo,
    float* __restrict__ S)
{
  // decode triangular index: bid -> (bi >= bj)
  int bid = blockIdx.x;
  int bi = (int)((sqrtf(8.f * (float)bid + 1.f) - 1.f) * 0.5f);
  while ((bi + 1) * (bi + 2) / 2 <= bid) bi++;
  while (bi * (bi + 1) / 2 > bid) bi--;
  int bj = bid - bi * (bi + 1) / 2;

  __shared__ unsigned short Ahi[128 * BK], Alo[128 * BK];
  __shared__ unsigned short Bhi[128 * BK], Blo[128 * BK];
  int b  = blockIdx.y;
  int i0 = bi * 128, j0 = bj * 128;
  const unsigned short* Ah_g = Qhi + (size_t)(b * TT + i0) * DD;
  const unsigned short* Al_g = Qlo + (size_t)(b * TT + i0) * DD;
  const unsigned short* Bh_g = Khi + (size_t)(b * TT + j0) * DD;
  const unsigned short* Bl_g = Klo + (size_t)(b * TT + j0) * DD;
  int t = threadIdx.x;
  int lane = t & 63, w = t >> 6;
  int mw = (w >> 1) << 6, nw = (w & 1) << 6;
  int frow = lane & 15, fk = (lane >> 4) << 3;

  f32x4 acc[4][4];
#pragma unroll
  for (int a = 0; a < 4; a++)
#pragma unroll
    for (int c = 0; c < 4; c++){ f32x4 zz = {0.f,0.f,0.f,0.f}; acc[a][c] = zz; }

  for (int kk = 0; kk < DD / BK; kk++){
    int k0 = kk * BK;
    stage_async(Ah_g + k0, DD, Ahi, t);
    stage_async(Al_g + k0, DD, Alo, t);
    stage_async(Bh_g + k0, DD, Bhi, t);
    stage_async(Bl_g + k0, DD, Blo, t);
    __syncthreads();

    bf16x8 ah[4], al[4], bh[4], bl[4];
#pragma unroll
    for (int tm = 0; tm < 4; tm++){
      int off = (mw + tm * 16 + frow) * BK + fk;
      ah[tm] = ld8(&Ahi[off]); al[tm] = ld8(&Alo[off]);
    }
#pragma unroll
    for (int tn = 0; tn < 4; tn++){
      int off = (nw + tn * 16 + frow) * BK + fk;
      bh[tn] = ld8(&Bhi[off]); bl[tn] = ld8(&Blo[off]);
    }
#pragma unroll
    for (int tm = 0; tm < 4; tm++)
#pragma unroll
      for (int tn = 0; tn < 4; tn++){
        acc[tm][tn] = mfma16(ah[tm], bh[tn], acc[tm][tn]);
        acc[tm][tn] = mfma16(ah[tm], bl[tn], acc[tm][tn]);
        acc[tm][tn] = mfma16(al[tm], bh[tn], acc[tm][tn]);
      }
    __syncthreads();
  }

#pragma unroll
  for (int tm = 0; tm < 4; tm++)
#pragma unroll
    for (int tn = 0; tn < 4; tn++)
#pragma unroll
      for (int r = 0; r < 4; r++){
        int gi = i0 + mw + tm * 16 + ((lane >> 4) << 2) + r;
        int gj = j0 + nw + tn * 16 + frow;
        S[((size_t)(b * TT + gi) * TT) + gj] = acc[tm][tn][r] * 0.03125f;
      }
}

// ---------------- kernel 4: row softmax, single pass over S, P in bf16 ----------------
__global__ __launch_bounds__(256) void softmax_kernel(
    const float* __restrict__ S, unsigned short* __restrict__ P)
{
  int i = blockIdx.x, b = blockIdx.y;
  const float* s = S + (size_t)(b * TT + i) * TT;
  unsigned short* p = P + (size_t)(b * TT + i) * TT;
  int n = i + 1;
  int npad = ((i >> 7) + 1) << 7;   // pad to end of the diagonal 128-block
  int t = threadIdx.x;
  __shared__ float red[256];

  float v[8];
  float mx = -1e30f;
#pragma unroll
  for (int j = 0; j < 8; j++){
    int idx = t + j * 256;
    v[j] = (idx < n) ? s[idx] : -1e30f;
    mx = fmaxf(mx, v[j]);
  }
  red[t] = mx; __syncthreads();
  for (int k = 128; k > 0; k >>= 1){ if (t < k) red[t] = fmaxf(red[t], red[t + k]); __syncthreads(); }
  mx = red[0]; __syncthreads();

  float sum = 0.f;
#pragma unroll
  for (int j = 0; j < 8; j++){
    v[j] = (t + j * 256 < n) ? __expf(v[j] - mx) : 0.0f;
    sum += v[j];
  }
  red[t] = sum; __syncthreads();
  for (int k = 128; k > 0; k >>= 1){ if (t < k) red[t] += red[t + k]; __syncthreads(); }
  float inv = 1.0f / red[0];

#pragma unroll
  for (int j = 0; j < 8; j++){
    int idx = t + j * 256;
    if (idx < npad) p[idx] = f2bf(v[j] * inv);
  }
}

// ---------------- kernel 5: O = P V  (plain bf16, causal K-range, heavy blocks first) ----------------
__global__ __launch_bounds__(256) void pv_kernel(
    const unsigned short* __restrict__ P, const unsigned short* __restrict__ VT,
    float* __restrict__ O)
{
  __shared__ unsigned short At[128 * BK];
  __shared__ unsigned short Bt[128 * BK];
  int b  = blockIdx.z;
  int by = (int)gridDim.y - 1 - blockIdx.y;     // reversed: heavy blocks dispatch first
  int i0 = by * 128, n0 = blockIdx.x * 128;
  int ksteps = (by + 1) * 4;   // K runs over s < (by+1)*128
  const unsigned short* A_g = P  + (size_t)(b * TT + i0) * TT;
  const unsigned short* B_g = VT + (size_t)(b * DD + n0) * TT;
  int t = threadIdx.x;
  int lane = t & 63, w = t >> 6;
  int mw = (w >> 1) << 6, nw = (w & 1) << 6;
  int frow = lane & 15, fk = (lane >> 4) << 3;

  f32x4 acc[4][4];
#pragma unroll
  for (int a = 0; a < 4; a++)
#pragma unroll
    for (int c = 0; c < 4; c++){ f32x4 zz = {0.f,0.f,0.f,0.f}; acc[a][c] = zz; }

  for (int kk = 0; kk < ksteps; kk++){
    int k0 = kk * BK;
    stage_async(A_g + k0, TT, At, t);
    stage_async(B_g + k0, TT, Bt, t);
    __syncthreads();

    bf16x8 af[4], bf[4];
#pragma unroll
    for (int tm = 0; tm < 4; tm++) af[tm] = ld8(&At[(mw + tm * 16 + frow) * BK + fk]);
#pragma unroll
    for (int tn = 0; tn < 4; tn++) bf[tn] = ld8(&Bt[(nw + tn * 16 + frow) * BK + fk]);
#pragma unroll
    for (int tm = 0; tm < 4; tm++)
#pragma unroll
      for (int tn = 0; tn < 4; tn++)
        acc[tm][tn] = mfma16(af[tm], bf[tn], acc[tm][tn]);
    __syncthreads();
  }

#pragma unroll
  for (int tm = 0; tm < 4; tm++)
#pragma unroll
    for (int tn = 0; tn < 4; tn++)
#pragma unroll
      for (int r = 0; r < 4; r++){
        int gi = i0 + mw + tm * 16 + ((lane >> 4) << 2) + r;
        int gd = n0 + nw + tn * 16 + frow;
        O[(size_t)(b * TT + gi) * DD + gd] = acc[tm][tn][r];
      }
}

extern "C" void kernel_launch(void* const* d_in, const int* in_sizes, int n_in,
                              void* d_out, int out_size, void* d_ws, size_t ws_size,
                              hipStream_t stream) {
  const float* X  = (const float*)d_in[0];
  const float* Wq = (const float*)d_in[1];
  const float* Wk = (const float*)d_in[2];
  const float* Wv = (const float*)d_in[3];
  float* Out = (float*)d_out;

  unsigned short* Wthi = (unsigned short*)d_ws;          // 3 * 1M ushorts
  unsigned short* Wtlo = Wthi + 3u * 1048576u;           // 3 * 1M
  unsigned short* Qhi  = Wtlo + 3u * 1048576u;           // 8M ushorts each below
  unsigned short* Qlo  = Qhi + 8388608u;
  unsigned short* Khi  = Qlo + 8388608u;
  unsigned short* Klo  = Khi + 8388608u;
  unsigned short* VT   = Klo + 8388608u;
  float*          S    = (float*)(VT + 8388608u);        // 16M floats (64 MB)
  unsigned short* P    = (unsigned short*)(S + 16777216u); // 16M bf16 (32 MB)
  // Xhi/Xlo alias the S region (S is first written by qk_kernel, after proj_kernel
  // has finished reading Xhi/Xlo) -> total ws stays ~188 MB.
  unsigned short* Xhi  = (unsigned short*)S;             // 8M ushorts
  unsigned short* Xlo  = Xhi + 8388608u;                 // 8M ushorts

  dim3 blk(256);
  splitx_kernel<<<dim3(8192), blk, 0, stream>>>(X, Xhi, Xlo);
  wt_kernel<<<dim3(32, 32, 3), blk, 0, stream>>>(Wq, Wk, Wv, Wthi, Wtlo);
  proj_kernel<<<dim3(8, 64, 2), blk, 0, stream>>>(Xhi, Xlo, Wthi, Wtlo, Qhi, Qlo, Khi, Klo, VT);
  qk_kernel<<<dim3(136, 4), blk, 0, stream>>>(Qhi, Qlo, Khi, Klo, S);
  softmax_kernel<<<dim3(2048, 4, 1), blk, 0, stream>>>(S, P);
  pv_kernel<<<dim3(8, 16, 4), blk, 0, stream>>>(P, VT, Out);
}

// Round 4
// 383.015 us; speedup vs baseline: 1.1516x; 1.0059x over previous
//
#include <hip/hip_runtime.h>

#define TT   2048
#define DD   1024
#define BK   32          // K-tile; LDS tiles are contiguous [128][32] (global_load_lds needs lane-order layout)

typedef float  f32x4  __attribute__((ext_vector_type(4)));
typedef __bf16 bf16x8 __attribute__((ext_vector_type(8)));

static __device__ __forceinline__ unsigned short f2bf(float f){
  unsigned int u = __float_as_uint(f);
  return (unsigned short)((u + 0x7fffu + ((u >> 16) & 1u)) >> 16);   // RNE
}
static __device__ __forceinline__ float bf2f(unsigned short h){
  return __uint_as_float(((unsigned int)h) << 16);
}
static __device__ __forceinline__ bf16x8 ld8(const unsigned short* p){
  return *(const bf16x8*)p;
}
static __device__ __forceinline__ f32x4 mfma16(bf16x8 a, bf16x8 b, f32x4 c){
  return __builtin_amdgcn_mfma_f32_16x16x32_bf16(a, b, c, 0, 0, 0);
}

// async 16B global->LDS (direct, no VGPR round-trip)
static __device__ __forceinline__ void async16(
    const unsigned short* g, unsigned short* l)
{
  __builtin_amdgcn_global_load_lds(
      (const __attribute__((address_space(1))) unsigned int*)g,
      (__attribute__((address_space(3))) unsigned int*)l, 16, 0, 0);
}

// stage 128 rows x 32 cols of ushort from global (row-major, row_stride) into
// contiguous LDS tile [128][32]. Per thread: 2 x 16B. LDS dst = wave base + lane*16.
static __device__ __forceinline__ void stage_async(
    const unsigned short* __restrict__ src, int row_stride,
    unsigned short* __restrict__ dst, int t)
{
#pragma unroll
  for (int j = 0; j < 2; j++){
    int e = (t + j * 256) * 8;          // ushort index in tile
    int row = e >> 5, col = e & 31;
    async16(src + (size_t)row * row_stride + col, dst + e);
  }
}

// ---------------- kernel 0: split X, Wq, Wk (flat); transpose+split Wv ----------------
// grid: [0,8192) X | [8192,9216) Wq | [9216,10240) Wk | [10240,11264) Wv transpose tiles
__global__ __launch_bounds__(256) void split_all_kernel(
    const float* __restrict__ X,  const float* __restrict__ Wq,
    const float* __restrict__ Wk, const float* __restrict__ Wv,
    unsigned short* __restrict__ Xhi,  unsigned short* __restrict__ Xlo,
    unsigned short* __restrict__ Wqhi, unsigned short* __restrict__ Wqlo,
    unsigned short* __restrict__ Wkhi, unsigned short* __restrict__ Wklo,
    unsigned short* __restrict__ WvThi)
{
  __shared__ float tile[32][33];
  int bx = blockIdx.x;
  if (bx < 10240){
    const float* src; unsigned short *hi, *lo; size_t base;
    if (bx < 8192)      { src = X;  hi = Xhi;  lo = Xlo;  base = (size_t)bx * 1024; }
    else if (bx < 9216) { src = Wq; hi = Wqhi; lo = Wqlo; base = (size_t)(bx - 8192) * 1024; }
    else                { src = Wk; hi = Wkhi; lo = Wklo; base = (size_t)(bx - 9216) * 1024; }
    size_t i = base + (size_t)threadIdx.x * 4;
    const float4 x = *(const float4*)(src + i);
    ushort4 h, l;
    h.x = f2bf(x.x); l.x = f2bf(x.x - bf2f(h.x));
    h.y = f2bf(x.y); l.y = f2bf(x.y - bf2f(h.y));
    h.z = f2bf(x.z); l.z = f2bf(x.z - bf2f(h.z));
    h.w = f2bf(x.w); l.w = f2bf(x.w - bf2f(h.w));
    *(ushort4*)(hi + i) = h;
    *(ushort4*)(lo + i) = l;
  } else {
    // Wv transpose (hi only): WvT[n][d] = Wv[d][n]
    int tid = bx - 10240;
    int k0 = (tid & 31) * 32, n0 = (tid >> 5) * 32;
    int tx = threadIdx.x & 31, ty = threadIdx.x >> 5;
#pragma unroll
    for (int r = 0; r < 4; r++){
      int row = ty + r * 8;
      tile[row][tx] = Wv[(size_t)(k0 + row) * DD + n0 + tx];
    }
    __syncthreads();
#pragma unroll
    for (int r = 0; r < 4; r++){
      int nrow = ty + r * 8;
      float v = tile[tx][nrow];                 // = Wv[k0+tx][n0+nrow]
      WvThi[(size_t)(n0 + nrow) * DD + k0 + tx] = f2bf(v);
    }
  }
}

// ---------------- kernel 1: MT[e][d] = sum_n Wk[e][n]*Wq[d][n]  (split 3x) ----------------
__global__ __launch_bounds__(256) void mt_kernel(
    const unsigned short* __restrict__ Wkhi, const unsigned short* __restrict__ Wklo,
    const unsigned short* __restrict__ Wqhi, const unsigned short* __restrict__ Wqlo,
    unsigned short* __restrict__ MThi, unsigned short* __restrict__ MTlo)
{
  __shared__ unsigned short Ahi[128 * BK], Alo[128 * BK];
  __shared__ unsigned short Bhi[128 * BK], Blo[128 * BK];
  int e0 = blockIdx.y * 128, d0 = blockIdx.x * 128;
  const unsigned short* Ah_g = Wkhi + (size_t)e0 * DD;
  const unsigned short* Al_g = Wklo + (size_t)e0 * DD;
  const unsigned short* Bh_g = Wqhi + (size_t)d0 * DD;
  const unsigned short* Bl_g = Wqlo + (size_t)d0 * DD;
  int t = threadIdx.x;
  int lane = t & 63, w = t >> 6;
  int mw = (w >> 1) << 6, nw = (w & 1) << 6;
  int frow = lane & 15, fk = (lane >> 4) << 3;

  f32x4 acc[4][4];
#pragma unroll
  for (int a = 0; a < 4; a++)
#pragma unroll
    for (int c = 0; c < 4; c++){ f32x4 zz = {0.f,0.f,0.f,0.f}; acc[a][c] = zz; }

  for (int kk = 0; kk < DD / BK; kk++){
    int k0 = kk * BK;
    stage_async(Ah_g + k0, DD, Ahi, t);
    stage_async(Al_g + k0, DD, Alo, t);
    stage_async(Bh_g + k0, DD, Bhi, t);
    stage_async(Bl_g + k0, DD, Blo, t);
    __syncthreads();

    bf16x8 ah[4], al[4], bh[4], bl[4];
#pragma unroll
    for (int tm = 0; tm < 4; tm++){
      int off = (mw + tm * 16 + frow) * BK + fk;
      ah[tm] = ld8(&Ahi[off]); al[tm] = ld8(&Alo[off]);
    }
#pragma unroll
    for (int tn = 0; tn < 4; tn++){
      int off = (nw + tn * 16 + frow) * BK + fk;
      bh[tn] = ld8(&Bhi[off]); bl[tn] = ld8(&Blo[off]);
    }
#pragma unroll
    for (int tm = 0; tm < 4; tm++)
#pragma unroll
      for (int tn = 0; tn < 4; tn++){
        acc[tm][tn] = mfma16(ah[tm], bh[tn], acc[tm][tn]);
        acc[tm][tn] = mfma16(ah[tm], bl[tn], acc[tm][tn]);
        acc[tm][tn] = mfma16(al[tm], bh[tn], acc[tm][tn]);
      }
    __syncthreads();
  }

#pragma unroll
  for (int tm = 0; tm < 4; tm++)
#pragma unroll
    for (int tn = 0; tn < 4; tn++)
#pragma unroll
      for (int r = 0; r < 4; r++){
        float v = acc[tm][tn][r];
        int ge = e0 + mw + tm * 16 + ((lane >> 4) << 2) + r;
        int gd = d0 + nw + tn * 16 + frow;
        size_t idx = (size_t)ge * DD + gd;
        unsigned short h = f2bf(v);
        MThi[idx] = h; MTlo[idx] = f2bf(v - bf2f(h));
      }
}

// ---------------- kernel 2: Y = X*M (split 3x) merged with V = X*Wv (plain) ----------------
__global__ __launch_bounds__(256, 2) void y_kernel(
    const unsigned short* __restrict__ Xhi, const unsigned short* __restrict__ Xlo,
    const unsigned short* __restrict__ MThi, const unsigned short* __restrict__ MTlo,
    const unsigned short* __restrict__ WvThi,
    unsigned short* __restrict__ Yhi, unsigned short* __restrict__ Ylo,
    unsigned short* __restrict__ VT)
{
  __shared__ unsigned short Ahs[128 * BK], Als[128 * BK];
  __shared__ unsigned short Bmh[128 * BK], Bml[128 * BK], Bvh[128 * BK];
  int m0 = blockIdx.y * 128, n0 = blockIdx.x * 128;
  const unsigned short* Ah_g  = Xhi   + (size_t)m0 * DD;
  const unsigned short* Al_g  = Xlo   + (size_t)m0 * DD;
  const unsigned short* Bmh_g = MThi  + (size_t)n0 * DD;
  const unsigned short* Bml_g = MTlo  + (size_t)n0 * DD;
  const unsigned short* Bvh_g = WvThi + (size_t)n0 * DD;
  int t = threadIdx.x;
  int lane = t & 63, w = t >> 6;
  int mw = (w >> 1) << 6, nw = (w & 1) << 6;
  int frow = lane & 15, fk = (lane >> 4) << 3;

  f32x4 accY[4][4], accV[4][4];
#pragma unroll
  for (int a = 0; a < 4; a++)
#pragma unroll
    for (int c = 0; c < 4; c++){
      f32x4 zz = {0.f,0.f,0.f,0.f}; accY[a][c] = zz; accV[a][c] = zz;
    }

  for (int kk = 0; kk < DD / BK; kk++){
    int k0 = kk * BK;
    stage_async(Ah_g  + k0, DD, Ahs, t);
    stage_async(Al_g  + k0, DD, Als, t);
    stage_async(Bmh_g + k0, DD, Bmh, t);
    stage_async(Bml_g + k0, DD, Bml, t);
    stage_async(Bvh_g + k0, DD, Bvh, t);
    __syncthreads();

    bf16x8 ah[4], al[4];
#pragma unroll
    for (int tm = 0; tm < 4; tm++){
      int off = (mw + tm * 16 + frow) * BK + fk;
      ah[tm] = ld8(&Ahs[off]); al[tm] = ld8(&Als[off]);
    }
#pragma unroll
    for (int tn = 0; tn < 4; tn++){
      int off = (nw + tn * 16 + frow) * BK + fk;
      bf16x8 bmh = ld8(&Bmh[off]), bml = ld8(&Bml[off]), bvh = ld8(&Bvh[off]);
#pragma unroll
      for (int tm = 0; tm < 4; tm++){
        accY[tm][tn] = mfma16(ah[tm], bmh, accY[tm][tn]);
        accY[tm][tn] = mfma16(ah[tm], bml, accY[tm][tn]);
        accY[tm][tn] = mfma16(al[tm], bmh, accY[tm][tn]);
        accV[tm][tn] = mfma16(ah[tm], bvh, accV[tm][tn]);
      }
    }
    __syncthreads();
  }

#pragma unroll
  for (int tm = 0; tm < 4; tm++)
#pragma unroll
    for (int tn = 0; tn < 4; tn++)
#pragma unroll
      for (int r = 0; r < 4; r++){
        int grow = m0 + mw + tm * 16 + ((lane >> 4) << 2) + r;
        int gcol = n0 + nw + tn * 16 + frow;
        size_t idx = (size_t)grow * DD + gcol;
        float vy = accY[tm][tn][r];
        unsigned short hy = f2bf(vy);
        Yhi[idx] = hy; Ylo[idx] = f2bf(vy - bf2f(hy));
        int b = grow >> 11, tl = grow & 2047;
        VT[((size_t)(b * DD + gcol) << 11) | tl] = f2bf(accV[tm][tn][r]);
      }
}

// ---------------- kernel 3: S = (Y X^T) / 32, triangular grid ----------------
__global__ __launch_bounds__(256) void s_kernel(
    const unsigned short* __restrict__ Yhi, const unsigned short* __restrict__ Ylo,
    const unsigned short* __restrict__ Xhi, const unsigned short* __restrict__ Xlo,
    float* __restrict__ S)
{
  int bid = blockIdx.x;
  int bi = (int)((sqrtf(8.f * (float)bid + 1.f) - 1.f) * 0.5f);
  while ((bi + 1) * (bi + 2) / 2 <= bid) bi++;
  while (bi * (bi + 1) / 2 > bid) bi--;
  int bj = bid - bi * (bi + 1) / 2;

  __shared__ unsigned short Ahi[128 * BK], Alo[128 * BK];
  __shared__ unsigned short Bhi[128 * BK], Blo[128 * BK];
  int b  = blockIdx.y;
  int i0 = bi * 128, j0 = bj * 128;
  const unsigned short* Ah_g = Yhi + (size_t)(b * TT + i0) * DD;
  const unsigned short* Al_g = Ylo + (size_t)(b * TT + i0) * DD;
  const unsigned short* Bh_g = Xhi + (size_t)(b * TT + j0) * DD;
  const unsigned short* Bl_g = Xlo + (size_t)(b * TT + j0) * DD;
  int t = threadIdx.x;
  int lane = t & 63, w = t >> 6;
  int mw = (w >> 1) << 6, nw = (w & 1) << 6;
  int frow = lane & 15, fk = (lane >> 4) << 3;

  f32x4 acc[4][4];
#pragma unroll
  for (int a = 0; a < 4; a++)
#pragma unroll
    for (int c = 0; c < 4; c++){ f32x4 zz = {0.f,0.f,0.f,0.f}; acc[a][c] = zz; }

  for (int kk = 0; kk < DD / BK; kk++){
    int k0 = kk * BK;
    stage_async(Ah_g + k0, DD, Ahi, t);
    stage_async(Al_g + k0, DD, Alo, t);
    stage_async(Bh_g + k0, DD, Bhi, t);
    stage_async(Bl_g + k0, DD, Blo, t);
    __syncthreads();

    bf16x8 ah[4], al[4], bh[4], bl[4];
#pragma unroll
    for (int tm = 0; tm < 4; tm++){
      int off = (mw + tm * 16 + frow) * BK + fk;
      ah[tm] = ld8(&Ahi[off]); al[tm] = ld8(&Alo[off]);
    }
#pragma unroll
    for (int tn = 0; tn < 4; tn++){
      int off = (nw + tn * 16 + frow) * BK + fk;
      bh[tn] = ld8(&Bhi[off]); bl[tn] = ld8(&Blo[off]);
    }
#pragma unroll
    for (int tm = 0; tm < 4; tm++)
#pragma unroll
      for (int tn = 0; tn < 4; tn++){
        acc[tm][tn] = mfma16(ah[tm], bh[tn], acc[tm][tn]);
        acc[tm][tn] = mfma16(ah[tm], bl[tn], acc[tm][tn]);
        acc[tm][tn] = mfma16(al[tm], bh[tn], acc[tm][tn]);
      }
    __syncthreads();
  }

#pragma unroll
  for (int tm = 0; tm < 4; tm++)
#pragma unroll
    for (int tn = 0; tn < 4; tn++)
#pragma unroll
      for (int r = 0; r < 4; r++){
        int gi = i0 + mw + tm * 16 + ((lane >> 4) << 2) + r;
        int gj = j0 + nw + tn * 16 + frow;
        S[((size_t)(b * TT + gi) * TT) + gj] = acc[tm][tn][r] * 0.03125f;
      }
}

// ---------------- kernel 4: row softmax, single pass over S, P in bf16 ----------------
__global__ __launch_bounds__(256) void softmax_kernel(
    const float* __restrict__ S, unsigned short* __restrict__ P)
{
  int i = blockIdx.x, b = blockIdx.y;
  const float* s = S + (size_t)(b * TT + i) * TT;
  unsigned short* p = P + (size_t)(b * TT + i) * TT;
  int n = i + 1;
  int npad = ((i >> 7) + 1) << 7;   // pad to end of the diagonal 128-block
  int t = threadIdx.x;
  __shared__ float red[256];

  float v[8];
  float mx = -1e30f;
#pragma unroll
  for (int j = 0; j < 8; j++){
    int idx = t + j * 256;
    v[j] = (idx < n) ? s[idx] : -1e30f;
    mx = fmaxf(mx, v[j]);
  }
  red[t] = mx; __syncthreads();
  for (int k = 128; k > 0; k >>= 1){ if (t < k) red[t] = fmaxf(red[t], red[t + k]); __syncthreads(); }
  mx = red[0]; __syncthreads();

  float sum = 0.f;
#pragma unroll
  for (int j = 0; j < 8; j++){
    v[j] = (t + j * 256 < n) ? __expf(v[j] - mx) : 0.0f;
    sum += v[j];
  }
  red[t] = sum; __syncthreads();
  for (int k = 128; k > 0; k >>= 1){ if (t < k) red[t] += red[t + k]; __syncthreads(); }
  float inv = 1.0f / red[0];

#pragma unroll
  for (int j = 0; j < 8; j++){
    int idx = t + j * 256;
    if (idx < npad) p[idx] = f2bf(v[j] * inv);
  }
}

// ---------------- kernel 5: O = P V  (plain bf16, causal K-range, heavy blocks first) ----------------
__global__ __launch_bounds__(256) void pv_kernel(
    const unsigned short* __restrict__ P, const unsigned short* __restrict__ VT,
    float* __restrict__ O)
{
  __shared__ unsigned short At[128 * BK];
  __shared__ unsigned short Bt[128 * BK];
  int b  = blockIdx.z;
  int by = (int)gridDim.y - 1 - blockIdx.y;     // reversed: heavy blocks dispatch first
  int i0 = by * 128, n0 = blockIdx.x * 128;
  int ksteps = (by + 1) * 4;   // K runs over s < (by+1)*128
  const unsigned short* A_g = P  + (size_t)(b * TT + i0) * TT;
  const unsigned short* B_g = VT + (size_t)(b * DD + n0) * TT;
  int t = threadIdx.x;
  int lane = t & 63, w = t >> 6;
  int mw = (w >> 1) << 6, nw = (w & 1) << 6;
  int frow = lane & 15, fk = (lane >> 4) << 3;

  f32x4 acc[4][4];
#pragma unroll
  for (int a = 0; a < 4; a++)
#pragma unroll
    for (int c = 0; c < 4; c++){ f32x4 zz = {0.f,0.f,0.f,0.f}; acc[a][c] = zz; }

  for (int kk = 0; kk < ksteps; kk++){
    int k0 = kk * BK;
    stage_async(A_g + k0, TT, At, t);
    stage_async(B_g + k0, TT, Bt, t);
    __syncthreads();

    bf16x8 af[4], bf[4];
#pragma unroll
    for (int tm = 0; tm < 4; tm++) af[tm] = ld8(&At[(mw + tm * 16 + frow) * BK + fk]);
#pragma unroll
    for (int tn = 0; tn < 4; tn++) bf[tn] = ld8(&Bt[(nw + tn * 16 + frow) * BK + fk]);
#pragma unroll
    for (int tm = 0; tm < 4; tm++)
#pragma unroll
      for (int tn = 0; tn < 4; tn++)
        acc[tm][tn] = mfma16(af[tm], bf[tn], acc[tm][tn]);
    __syncthreads();
  }

#pragma unroll
  for (int tm = 0; tm < 4; tm++)
#pragma unroll
    for (int tn = 0; tn < 4; tn++)
#pragma unroll
      for (int r = 0; r < 4; r++){
        int gi = i0 + mw + tm * 16 + ((lane >> 4) << 2) + r;
        int gd = n0 + nw + tn * 16 + frow;
        O[(size_t)(b * TT + gi) * DD + gd] = acc[tm][tn][r];
      }
}

extern "C" void kernel_launch(void* const* d_in, const int* in_sizes, int n_in,
                              void* d_out, int out_size, void* d_ws, size_t ws_size,
                              hipStream_t stream) {
  const float* X  = (const float*)d_in[0];
  const float* Wq = (const float*)d_in[1];
  const float* Wk = (const float*)d_in[2];
  const float* Wv = (const float*)d_in[3];
  float* Out = (float*)d_out;

  const size_t M1 = 1048576u;
  unsigned short* base  = (unsigned short*)d_ws;
  unsigned short* Wqhi  = base;                 // 1M ushorts each
  unsigned short* Wqlo  = base + 1 * M1;
  unsigned short* Wkhi  = base + 2 * M1;
  unsigned short* Wklo  = base + 3 * M1;
  unsigned short* WvThi = base + 4 * M1;
  unsigned short* MThi  = base + 5 * M1;
  unsigned short* MTlo  = base + 6 * M1;
  unsigned short* Xhi   = base + 7 * M1;        // 8M ushorts each
  unsigned short* Xlo   = base + 15 * M1;
  unsigned short* Yhi   = base + 23 * M1;
  unsigned short* Ylo   = base + 31 * M1;
  unsigned short* VT    = base + 39 * M1;
  float*          S     = (float*)(base + 47 * M1);   // 16M floats (64 MB), ends at 158 MB
  // P aliases Xhi+Xlo (16M ushorts): X is dead after s_kernel, P written by softmax after.
  unsigned short* P     = Xhi;

  dim3 blk(256);
  split_all_kernel<<<dim3(11264), blk, 0, stream>>>(X, Wq, Wk, Wv,
      Xhi, Xlo, Wqhi, Wqlo, Wkhi, Wklo, WvThi);
  mt_kernel<<<dim3(8, 8), blk, 0, stream>>>(Wkhi, Wklo, Wqhi, Wqlo, MThi, MTlo);
  y_kernel<<<dim3(8, 64), blk, 0, stream>>>(Xhi, Xlo, MThi, MTlo, WvThi, Yhi, Ylo, VT);
  s_kernel<<<dim3(136, 4), blk, 0, stream>>>(Yhi, Ylo, Xhi, Xlo, S);
  softmax_kernel<<<dim3(2048, 4, 1), blk, 0, stream>>>(S, P);
  pv_kernel<<<dim3(8, 16, 4), blk, 0, stream>>>(P, VT, Out);
}

// Round 6
// 365.831 us; speedup vs baseline: 1.2057x; 1.0470x over previous
//
#include <hip/hip_runtime.h>

#define TT   2048
#define DD   1024
#define BK   32          // K-tile; LDS tiles are contiguous [128][32] (global_load_lds needs lane-order layout)

typedef float  f32x4  __attribute__((ext_vector_type(4)));
typedef __bf16 bf16x8 __attribute__((ext_vector_type(8)));

static __device__ __forceinline__ unsigned short f2bf(float f){
  unsigned int u = __float_as_uint(f);
  return (unsigned short)((u + 0x7fffu + ((u >> 16) & 1u)) >> 16);   // RNE
}
static __device__ __forceinline__ float bf2f(unsigned short h){
  return __uint_as_float(((unsigned int)h) << 16);
}
static __device__ __forceinline__ bf16x8 ld8(const unsigned short* p){
  return *(const bf16x8*)p;
}
static __device__ __forceinline__ f32x4 mfma16(bf16x8 a, bf16x8 b, f32x4 c){
  return __builtin_amdgcn_mfma_f32_16x16x32_bf16(a, b, c, 0, 0, 0);
}

// async 16B global->LDS (direct, no VGPR round-trip)
static __device__ __forceinline__ void async16(
    const unsigned short* g, unsigned short* l)
{
  __builtin_amdgcn_global_load_lds(
      (const __attribute__((address_space(1))) unsigned int*)g,
      (__attribute__((address_space(3))) unsigned int*)l, 16, 0, 0);
}

// stage 128 rows x 32 cols of ushort from global (row-major, row_stride) into
// contiguous LDS tile [128][32]. Per thread: 2 x 16B. LDS dst = wave base + lane*16.
static __device__ __forceinline__ void stage_async(
    const unsigned short* __restrict__ src, int row_stride,
    unsigned short* __restrict__ dst, int t)
{
#pragma unroll
  for (int j = 0; j < 2; j++){
    int e = (t + j * 256) * 8;          // ushort index in tile
    int row = e >> 5, col = e & 31;
    async16(src + (size_t)row * row_stride + col, dst + e);
  }
}

// ---------------- kernel 0: split X, Wq, Wk (flat); transpose+split Wv ----------------
// grid: [0,8192) X | [8192,9216) Wq | [9216,10240) Wk | [10240,11264) Wv transpose tiles
__global__ __launch_bounds__(256) void split_all_kernel(
    const float* __restrict__ X,  const float* __restrict__ Wq,
    const float* __restrict__ Wk, const float* __restrict__ Wv,
    unsigned short* __restrict__ Xhi,  unsigned short* __restrict__ Xlo,
    unsigned short* __restrict__ Wqhi, unsigned short* __restrict__ Wqlo,
    unsigned short* __restrict__ Wkhi, unsigned short* __restrict__ Wklo,
    unsigned short* __restrict__ WvThi)
{
  __shared__ float tile[32][33];
  int bx = blockIdx.x;
  if (bx < 10240){
    const float* src; unsigned short *hi, *lo; size_t base;
    if (bx < 8192)      { src = X;  hi = Xhi;  lo = Xlo;  base = (size_t)bx * 1024; }
    else if (bx < 9216) { src = Wq; hi = Wqhi; lo = Wqlo; base = (size_t)(bx - 8192) * 1024; }
    else                { src = Wk; hi = Wkhi; lo = Wklo; base = (size_t)(bx - 9216) * 1024; }
    size_t i = base + (size_t)threadIdx.x * 4;
    const float4 x = *(const float4*)(src + i);
    ushort4 h, l;
    h.x = f2bf(x.x); l.x = f2bf(x.x - bf2f(h.x));
    h.y = f2bf(x.y); l.y = f2bf(x.y - bf2f(h.y));
    h.z = f2bf(x.z); l.z = f2bf(x.z - bf2f(h.z));
    h.w = f2bf(x.w); l.w = f2bf(x.w - bf2f(h.w));
    *(ushort4*)(hi + i) = h;
    *(ushort4*)(lo + i) = l;
  } else {
    // Wv transpose (hi only): WvT[n][d] = Wv[d][n]
    int tid = bx - 10240;
    int k0 = (tid & 31) * 32, n0 = (tid >> 5) * 32;
    int tx = threadIdx.x & 31, ty = threadIdx.x >> 5;
#pragma unroll
    for (int r = 0; r < 4; r++){
      int row = ty + r * 8;
      tile[row][tx] = Wv[(size_t)(k0 + row) * DD + n0 + tx];
    }
    __syncthreads();
#pragma unroll
    for (int r = 0; r < 4; r++){
      int nrow = ty + r * 8;
      float v = tile[tx][nrow];                 // = Wv[k0+tx][n0+nrow]
      WvThi[(size_t)(n0 + nrow) * DD + k0 + tx] = f2bf(v);
    }
  }
}

// ---------------- kernel 1: MT[e][d] = sum_n Wk[e][n]*Wq[d][n]  (split 3x) ----------------
__global__ __launch_bounds__(256) void mt_kernel(
    const unsigned short* __restrict__ Wkhi, const unsigned short* __restrict__ Wklo,
    const unsigned short* __restrict__ Wqhi, const unsigned short* __restrict__ Wqlo,
    unsigned short* __restrict__ MThi, unsigned short* __restrict__ MTlo)
{
  __shared__ unsigned short Ahi[128 * BK], Alo[128 * BK];
  __shared__ unsigned short Bhi[128 * BK], Blo[128 * BK];
  int e0 = blockIdx.y * 128, d0 = blockIdx.x * 128;
  const unsigned short* Ah_g = Wkhi + (size_t)e0 * DD;
  const unsigned short* Al_g = Wklo + (size_t)e0 * DD;
  const unsigned short* Bh_g = Wqhi + (size_t)d0 * DD;
  const unsigned short* Bl_g = Wqlo + (size_t)d0 * DD;
  int t = threadIdx.x;
  int lane = t & 63, w = t >> 6;
  int mw = (w >> 1) << 6, nw = (w & 1) << 6;
  int frow = lane & 15, fk = (lane >> 4) << 3;

  f32x4 acc[4][4];
#pragma unroll
  for (int a = 0; a < 4; a++)
#pragma unroll
    for (int c = 0; c < 4; c++){ f32x4 zz = {0.f,0.f,0.f,0.f}; acc[a][c] = zz; }

  for (int kk = 0; kk < DD / BK; kk++){
    int k0 = kk * BK;
    stage_async(Ah_g + k0, DD, Ahi, t);
    stage_async(Al_g + k0, DD, Alo, t);
    stage_async(Bh_g + k0, DD, Bhi, t);
    stage_async(Bl_g + k0, DD, Blo, t);
    __syncthreads();

    bf16x8 ah[4], al[4], bh[4], bl[4];
#pragma unroll
    for (int tm = 0; tm < 4; tm++){
      int off = (mw + tm * 16 + frow) * BK + fk;
      ah[tm] = ld8(&Ahi[off]); al[tm] = ld8(&Alo[off]);
    }
#pragma unroll
    for (int tn = 0; tn < 4; tn++){
      int off = (nw + tn * 16 + frow) * BK + fk;
      bh[tn] = ld8(&Bhi[off]); bl[tn] = ld8(&Blo[off]);
    }
#pragma unroll
    for (int tm = 0; tm < 4; tm++)
#pragma unroll
      for (int tn = 0; tn < 4; tn++){
        acc[tm][tn] = mfma16(ah[tm], bh[tn], acc[tm][tn]);
        acc[tm][tn] = mfma16(ah[tm], bl[tn], acc[tm][tn]);
        acc[tm][tn] = mfma16(al[tm], bh[tn], acc[tm][tn]);
      }
    __syncthreads();
  }

#pragma unroll
  for (int tm = 0; tm < 4; tm++)
#pragma unroll
    for (int tn = 0; tn < 4; tn++)
#pragma unroll
      for (int r = 0; r < 4; r++){
        float v = acc[tm][tn][r];
        int ge = e0 + mw + tm * 16 + ((lane >> 4) << 2) + r;
        int gd = d0 + nw + tn * 16 + frow;
        size_t idx = (size_t)ge * DD + gd;
        unsigned short h = f2bf(v);
        MThi[idx] = h; MTlo[idx] = f2bf(v - bf2f(h));
      }
}

// ---------------- kernel 2: Y = X*M (split 3x) merged with V = X*Wv (plain) ----------------
__global__ __launch_bounds__(256, 2) void y_kernel(
    const unsigned short* __restrict__ Xhi, const unsigned short* __restrict__ Xlo,
    const unsigned short* __restrict__ MThi, const unsigned short* __restrict__ MTlo,
    const unsigned short* __restrict__ WvThi,
    unsigned short* __restrict__ Yhi, unsigned short* __restrict__ Ylo,
    unsigned short* __restrict__ VT)
{
  __shared__ unsigned short Ahs[128 * BK], Als[128 * BK];
  __shared__ unsigned short Bmh[128 * BK], Bml[128 * BK], Bvh[128 * BK];
  int m0 = blockIdx.y * 128, n0 = blockIdx.x * 128;
  const unsigned short* Ah_g  = Xhi   + (size_t)m0 * DD;
  const unsigned short* Al_g  = Xlo   + (size_t)m0 * DD;
  const unsigned short* Bmh_g = MThi  + (size_t)n0 * DD;
  const unsigned short* Bml_g = MTlo  + (size_t)n0 * DD;
  const unsigned short* Bvh_g = WvThi + (size_t)n0 * DD;
  int t = threadIdx.x;
  int lane = t & 63, w = t >> 6;
  int mw = (w >> 1) << 6, nw = (w & 1) << 6;
  int frow = lane & 15, fk = (lane >> 4) << 3;

  f32x4 accY[4][4], accV[4][4];
#pragma unroll
  for (int a = 0; a < 4; a++)
#pragma unroll
    for (int c = 0; c < 4; c++){
      f32x4 zz = {0.f,0.f,0.f,0.f}; accY[a][c] = zz; accV[a][c] = zz;
    }

  for (int kk = 0; kk < DD / BK; kk++){
    int k0 = kk * BK;
    stage_async(Ah_g  + k0, DD, Ahs, t);
    stage_async(Al_g  + k0, DD, Als, t);
    stage_async(Bmh_g + k0, DD, Bmh, t);
    stage_async(Bml_g + k0, DD, Bml, t);
    stage_async(Bvh_g + k0, DD, Bvh, t);
    __syncthreads();

    bf16x8 ah[4], al[4];
#pragma unroll
    for (int tm = 0; tm < 4; tm++){
      int off = (mw + tm * 16 + frow) * BK + fk;
      ah[tm] = ld8(&Ahs[off]); al[tm] = ld8(&Als[off]);
    }
#pragma unroll
    for (int tn = 0; tn < 4; tn++){
      int off = (nw + tn * 16 + frow) * BK + fk;
      bf16x8 bmh = ld8(&Bmh[off]), bml = ld8(&Bml[off]), bvh = ld8(&Bvh[off]);
#pragma unroll
      for (int tm = 0; tm < 4; tm++){
        accY[tm][tn] = mfma16(ah[tm], bmh, accY[tm][tn]);
        accY[tm][tn] = mfma16(ah[tm], bml, accY[tm][tn]);
        accY[tm][tn] = mfma16(al[tm], bmh, accY[tm][tn]);
        accV[tm][tn] = mfma16(ah[tm], bvh, accV[tm][tn]);
      }
    }
    __syncthreads();
  }

#pragma unroll
  for (int tm = 0; tm < 4; tm++)
#pragma unroll
    for (int tn = 0; tn < 4; tn++)
#pragma unroll
      for (int r = 0; r < 4; r++){
        int grow = m0 + mw + tm * 16 + ((lane >> 4) << 2) + r;
        int gcol = n0 + nw + tn * 16 + frow;
        size_t idx = (size_t)grow * DD + gcol;
        float vy = accY[tm][tn][r];
        unsigned short hy = f2bf(vy);
        Yhi[idx] = hy; Ylo[idx] = f2bf(vy - bf2f(hy));
        int b = grow >> 11, tl = grow & 2047;
        VT[((size_t)(b * DD + gcol) << 11) | tl] = f2bf(accV[tm][tn][r]);
      }
}

// ---------------- kernel 3: S = (Y X^T) / 32 ----------------
// 544 units = 136 triangular tiles x 4 batches, flattened: u = tile*4 + batch.
// Grid 512: blocks 0..31 (dispatched first) take units {480+bx, 512+bx}; rest take bx-32.
__global__ __launch_bounds__(256) void s_kernel(
    const unsigned short* __restrict__ Yhi, const unsigned short* __restrict__ Ylo,
    const unsigned short* __restrict__ Xhi, const unsigned short* __restrict__ Xlo,
    float* __restrict__ S)
{
  __shared__ unsigned short Ahi[128 * BK], Alo[128 * BK];
  __shared__ unsigned short Bhi[128 * BK], Blo[128 * BK];
  int bx = blockIdx.x;                       // 0..511
  int nt = (bx < 32) ? 2 : 1;
  int u0 = (bx < 32) ? (480 + bx) : (bx - 32);
  int t = threadIdx.x;
  int lane = t & 63, w = t >> 6;
  int mw = (w >> 1) << 6, nw = (w & 1) << 6;
  int frow = lane & 15, fk = (lane >> 4) << 3;

  for (int sub = 0; sub < nt; sub++){
    int u = u0 + sub * 32;                   // 0..543
    int b = u & 3;
    int tid = u >> 2;                        // 0..135 triangular tile id
    int bi = (int)((sqrtf(8.f * (float)tid + 1.f) - 1.f) * 0.5f);
    while ((bi + 1) * (bi + 2) / 2 <= tid) bi++;
    while (bi * (bi + 1) / 2 > tid) bi--;
    int bj = tid - bi * (bi + 1) / 2;
    int i0 = bi * 128, j0 = bj * 128;
    const unsigned short* Ah_g = Yhi + (size_t)(b * TT + i0) * DD;
    const unsigned short* Al_g = Ylo + (size_t)(b * TT + i0) * DD;
    const unsigned short* Bh_g = Xhi + (size_t)(b * TT + j0) * DD;
    const unsigned short* Bl_g = Xlo + (size_t)(b * TT + j0) * DD;

    f32x4 acc[4][4];
#pragma unroll
    for (int a = 0; a < 4; a++)
#pragma unroll
      for (int c = 0; c < 4; c++){ f32x4 zz = {0.f,0.f,0.f,0.f}; acc[a][c] = zz; }

    for (int kk = 0; kk < DD / BK; kk++){
      int k0 = kk * BK;
      stage_async(Ah_g + k0, DD, Ahi, t);
      stage_async(Al_g + k0, DD, Alo, t);
      stage_async(Bh_g + k0, DD, Bhi, t);
      stage_async(Bl_g + k0, DD, Blo, t);
      __syncthreads();

      bf16x8 ah[4], al[4], bh[4], bl[4];
#pragma unroll
      for (int tm = 0; tm < 4; tm++){
        int off = (mw + tm * 16 + frow) * BK + fk;
        ah[tm] = ld8(&Ahi[off]); al[tm] = ld8(&Alo[off]);
      }
#pragma unroll
      for (int tn = 0; tn < 4; tn++){
        int off = (nw + tn * 16 + frow) * BK + fk;
        bh[tn] = ld8(&Bhi[off]); bl[tn] = ld8(&Blo[off]);
      }
#pragma unroll
      for (int tm = 0; tm < 4; tm++)
#pragma unroll
        for (int tn = 0; tn < 4; tn++){
          acc[tm][tn] = mfma16(ah[tm], bh[tn], acc[tm][tn]);
          acc[tm][tn] = mfma16(ah[tm], bl[tn], acc[tm][tn]);
          acc[tm][tn] = mfma16(al[tm], bh[tn], acc[tm][tn]);
        }
      __syncthreads();
    }

#pragma unroll
    for (int tm = 0; tm < 4; tm++)
#pragma unroll
      for (int tn = 0; tn < 4; tn++)
#pragma unroll
        for (int r = 0; r < 4; r++){
          int gi = i0 + mw + tm * 16 + ((lane >> 4) << 2) + r;
          int gj = j0 + nw + tn * 16 + frow;
          S[((size_t)(b * TT + gi) * TT) + gj] = acc[tm][tn][r] * 0.03125f;
        }
  }
}

// ---------------- kernel 4: row softmax, vectorized (float4 in, ushort4 out) ----------------
__global__ __launch_bounds__(256) void softmax_kernel(
    const float* __restrict__ S, unsigned short* __restrict__ P)
{
  int i = blockIdx.x, b = blockIdx.y;
  const float* s = S + (size_t)(b * TT + i) * TT;
  unsigned short* p = P + (size_t)(b * TT + i) * TT;
  int n = i + 1;
  int npad = ((i >> 7) + 1) << 7;   // pad to end of the diagonal 128-block (multiple of 4)
  int t = threadIdx.x;
  __shared__ float red[256];

  float v[8];
  float mx = -1e30f;
#pragma unroll
  for (int pas = 0; pas < 2; pas++){
    int idx = t * 4 + pas * 1024;
    if (idx + 3 < n){
      float4 x = *(const float4*)(s + idx);
      v[pas*4+0] = x.x; v[pas*4+1] = x.y; v[pas*4+2] = x.z; v[pas*4+3] = x.w;
    } else {
#pragma unroll
      for (int e = 0; e < 4; e++)
        v[pas*4+e] = (idx + e < n) ? s[idx + e] : -1e30f;
    }
#pragma unroll
    for (int e = 0; e < 4; e++) mx = fmaxf(mx, v[pas*4+e]);
  }
  red[t] = mx; __syncthreads();
  for (int k = 128; k > 0; k >>= 1){ if (t < k) red[t] = fmaxf(red[t], red[t + k]); __syncthreads(); }
  mx = red[0]; __syncthreads();

  float sum = 0.f;
#pragma unroll
  for (int j = 0; j < 8; j++){
    v[j] = __expf(v[j] - mx);          // masked entries: exp(-1e30 - mx) -> 0
    sum += v[j];
  }
  red[t] = sum; __syncthreads();
  for (int k = 128; k > 0; k >>= 1){ if (t < k) red[t] += red[t + k]; __syncthreads(); }
  float inv = 1.0f / red[0];

#pragma unroll
  for (int pas = 0; pas < 2; pas++){
    int idx = t * 4 + pas * 1024;
    if (idx < npad){
      ushort4 o;
      o.x = f2bf(v[pas*4+0] * inv);
      o.y = f2bf(v[pas*4+1] * inv);
      o.z = f2bf(v[pas*4+2] * inv);
      o.w = f2bf(v[pas*4+3] * inv);
      *(ushort4*)(p + idx) = o;
    }
  }
}

// ---------------- kernel 5: O = P V  (plain bf16, causal K-range, heavy blocks first) ----------------
__global__ __launch_bounds__(256) void pv_kernel(
    const unsigned short* __restrict__ P, const unsigned short* __restrict__ VT,
    float* __restrict__ O)
{
  __shared__ unsigned short At[128 * BK];
  __shared__ unsigned short Bt[128 * BK];
  int b  = blockIdx.z;
  int by = (int)gridDim.y - 1 - blockIdx.y;     // reversed: heavy blocks dispatch first
  int i0 = by * 128, n0 = blockIdx.x * 128;
  int ksteps = (by + 1) * 4;   // K runs over s < (by+1)*128
  const unsigned short* A_g = P  + (size_t)(b * TT + i0) * TT;
  const unsigned short* B_g = VT + (size_t)(b * DD + n0) * TT;
  int t = threadIdx.x;
  int lane = t & 63, w = t >> 6;
  int mw = (w >> 1) << 6, nw = (w & 1) << 6;
  int frow = lane & 15, fk = (lane >> 4) << 3;

  f32x4 acc[4][4];
#pragma unroll
  for (int a = 0; a < 4; a++)
#pragma unroll
    for (int c = 0; c < 4; c++){ f32x4 zz = {0.f,0.f,0.f,0.f}; acc[a][c] = zz; }

  for (int kk = 0; kk < ksteps; kk++){
    int k0 = kk * BK;
    stage_async(A_g + k0, TT, At, t);
    stage_async(B_g + k0, TT, Bt, t);
    __syncthreads();

    bf16x8 af[4], bf[4];
#pragma unroll
    for (int tm = 0; tm < 4; tm++) af[tm] = ld8(&At[(mw + tm * 16 + frow) * BK + fk]);
#pragma unroll
    for (int tn = 0; tn < 4; tn++) bf[tn] = ld8(&Bt[(nw + tn * 16 + frow) * BK + fk]);
#pragma unroll
    for (int tm = 0; tm < 4; tm++)
#pragma unroll
      for (int tn = 0; tn < 4; tn++)
        acc[tm][tn] = mfma16(af[tm], bf[tn], acc[tm][tn]);
    __syncthreads();
  }

#pragma unroll
  for (int tm = 0; tm < 4; tm++)
#pragma unroll
    for (int tn = 0; tn < 4; tn++)
#pragma unroll
      for (int r = 0; r < 4; r++){
        int gi = i0 + mw + tm * 16 + ((lane >> 4) << 2) + r;
        int gd = n0 + nw + tn * 16 + frow;
        O[(size_t)(b * TT + gi) * DD + gd] = acc[tm][tn][r];
      }
}

extern "C" void kernel_launch(void* const* d_in, const int* in_sizes, int n_in,
                              void* d_out, int out_size, void* d_ws, size_t ws_size,
                              hipStream_t stream) {
  const float* X  = (const float*)d_in[0];
  const float* Wq = (const float*)d_in[1];
  const float* Wk = (const float*)d_in[2];
  const float* Wv = (const float*)d_in[3];
  float* Out = (float*)d_out;

  const size_t M1 = 1048576u;
  unsigned short* base  = (unsigned short*)d_ws;
  unsigned short* Wqhi  = base;                 // 1M ushorts each
  unsigned short* Wqlo  = base + 1 * M1;
  unsigned short* Wkhi  = base + 2 * M1;
  unsigned short* Wklo  = base + 3 * M1;
  unsigned short* WvThi = base + 4 * M1;
  unsigned short* MThi  = base + 5 * M1;
  unsigned short* MTlo  = base + 6 * M1;
  unsigned short* Xhi   = base + 7 * M1;        // 8M ushorts each
  unsigned short* Xlo   = base + 15 * M1;
  unsigned short* Yhi   = base + 23 * M1;
  unsigned short* Ylo   = base + 31 * M1;
  unsigned short* VT    = base + 39 * M1;
  float*          S     = (float*)(base + 47 * M1);   // 16M floats (64 MB), ends at 158 MB
  // P aliases Xhi+Xlo (16M ushorts): X is dead after s_kernel, P written by softmax after.
  unsigned short* P     = Xhi;

  dim3 blk(256);
  split_all_kernel<<<dim3(11264), blk, 0, stream>>>(X, Wq, Wk, Wv,
      Xhi, Xlo, Wqhi, Wqlo, Wkhi, Wklo, WvThi);
  mt_kernel<<<dim3(8, 8), blk, 0, stream>>>(Wkhi, Wklo, Wqhi, Wqlo, MThi, MTlo);
  y_kernel<<<dim3(8, 64), blk, 0, stream>>>(Xhi, Xlo, MThi, MTlo, WvThi, Yhi, Ylo, VT);
  s_kernel<<<dim3(512), blk, 0, stream>>>(Yhi, Ylo, Xhi, Xlo, S);
  softmax_kernel<<<dim3(2048, 4, 1), blk, 0, stream>>>(S, P);
  pv_kernel<<<dim3(8, 16, 4), blk, 0, stream>>>(P, VT, Out);
}